// Round 14
// baseline (154.092 us; speedup 1.0000x reference)
//
#include <hip/hip_runtime.h>
#include <hip/hip_bf16.h>

// x: (2,32,32,480) fp32; qkv_w: (96,32,3,3); qkv_b: (96,); out_w: (32,32,3,3)
// D_MODEL=32, N_HEADS=8, dh=4, QUERY_SHAPE=24, MEM_FLANGE=8
// H=32, W=480, nb=20, wlen=40; per (b,h,blk): 768 queries x 1280 keys.

#define HW 15360      // 32*480, one channel plane
#define KEYS2 640     // keys per KSPLIT half
#define VS2 648       // Vl row stride in halves; 324 dw = 4 mod 32 -> rows on distinct banks

typedef _Float16 half4 __attribute__((ext_vector_type(4)));
typedef float floatx4 __attribute__((ext_vector_type(4)));

// ---------------------------------------------------------------------------
// Repack BOTH weight tensors [Cout][32][3][3] -> [32*9][Cout] in one launch.
// ---------------------------------------------------------------------------
__global__ __launch_bounds__(256) void repack_both(
    const float* __restrict__ w1, float* __restrict__ wt1,
    const float* __restrict__ w2, float* __restrict__ wt2) {
    int i = blockIdx.x * 256 + threadIdx.x;
    if (i < 96 * 288) {
        int co = i / 288, r = i - co * 288;
        wt1[r * 96 + co] = w1[i];
    } else if (i < 96 * 288 + 32 * 288) {
        int i2 = i - 96 * 288;
        int co = i2 / 288, r = i2 - co * 288;
        wt2[r * 32 + co] = w2[i2];
    }
}

// ---------------------------------------------------------------------------
// 3x3 conv, pad 1, NCHW, Cin=32. Each thread: 2 adjacent pixels (same row)
// x CO_TILE out-channels. 12 input loads serve 18 taps (2 pixels).
// ---------------------------------------------------------------------------
template<int CO_TILE, typename TIN, typename TOUT>
__global__ __launch_bounds__(256) void conv3x3_w2(
    const TIN* __restrict__ in, const float* __restrict__ wt,
    const float* __restrict__ bias, TOUT* __restrict__ out, int Cout)
{
    int nct = Cout / CO_TILE;
    int bc  = blockIdx.y;
    int ct  = bc % nct;
    int b   = bc / nct;
    int co0 = ct * CO_TILE;
    int pp  = blockIdx.x * 256 + threadIdx.x;   // < 7680
    int pix = pp * 2;
    int y   = pix / 480;
    int w   = pix - y * 480;                    // even, 0..478

    const TIN* ibase = in + (size_t)b * 32 * HW + y * 480 + w;

    bool ym = y > 0, yp = y < 31, wm = w > 0, wp = w < 478;
    const bool rok[3] = { ym, true, yp };
    const bool cok[4] = { wm, true, true, wp };
    int   off[12];
    float msk[12];
#pragma unroll
    for (int r = 0; r < 3; ++r)
#pragma unroll
        for (int c = 0; c < 4; ++c) {
            int k = r * 4 + c;
            bool v = rok[r] && cok[c];
            off[k] = v ? (r - 1) * 480 + (c - 1) : 0;
            msk[k] = v ? 1.f : 0.f;
        }

    float accA[CO_TILE], accB[CO_TILE];
#pragma unroll
    for (int i = 0; i < CO_TILE; ++i) {
        float bz = bias ? bias[co0 + i] : 0.f;
        accA[i] = bz; accB[i] = bz;
    }

    for (int ci = 0; ci < 32; ++ci) {
        const TIN* ip = ibase + ci * HW;
        float v[12];
#pragma unroll
        for (int k = 0; k < 12; ++k) v[k] = (float)ip[off[k]] * msk[k];

        const float* wrow = wt + ci * 9 * Cout + co0;
#pragma unroll
        for (int r = 0; r < 3; ++r)
#pragma unroll
            for (int c = 0; c < 3; ++c) {
                float xa = v[r * 4 + c];
                float xb = v[r * 4 + c + 1];
                const float4* w4p = (const float4*)(wrow + (r * 3 + c) * Cout);
#pragma unroll
                for (int q4 = 0; q4 < CO_TILE / 4; ++q4) {
                    float4 ww = w4p[q4];
                    accA[q4 * 4 + 0] += xa * ww.x;  accB[q4 * 4 + 0] += xb * ww.x;
                    accA[q4 * 4 + 1] += xa * ww.y;  accB[q4 * 4 + 1] += xb * ww.y;
                    accA[q4 * 4 + 2] += xa * ww.z;  accB[q4 * 4 + 2] += xb * ww.z;
                    accA[q4 * 4 + 3] += xa * ww.w;  accB[q4 * 4 + 3] += xb * ww.w;
                }
            }
    }

    size_t obase = (size_t)(b * Cout + co0) * HW + pix;
#pragma unroll
    for (int i = 0; i < CO_TILE; ++i) {
        struct alignas(2 * sizeof(TOUT)) P2 { TOUT a, b; };
        *(P2*)&out[obase + (size_t)i * HW] = P2{ (TOUT)accA[i], (TOUT)accB[i] };
    }
}

// ---------------------------------------------------------------------------
// MFMA flash attention, pass 1 (KSPLIT=2 over keys, for occupancy).
// Grid: 2560 WGs = (b,h,blk) x 4 query-groups x 2 key-halves, XCD-swizzled.
// 256 threads (4 waves), each wave 3 q-tiles of 16 queries, 640 keys in LDS
// (11.6 KB). S' = K·Q^T via mfma_16x16x16_f16 (swapped operands: C-frag of
// S' == A-frag of P), exp2 in-register, P·[V|1|0] second MFMA; ones-row of
// V^T accumulates the softmax denominator. Partials (4 dims + denom) -> ws.
// ---------------------------------------------------------------------------
__global__ __launch_bounds__(256) void attn_part(
    const _Float16* __restrict__ qkv, float* __restrict__ part)
{
    __shared__ _Float16 Kl[KEYS2 * 4];   // [j][d] key-major, 8B/key
    __shared__ _Float16 Vl[5 * VS2];     // [n][j] transposed; row 4 = ones
    __shared__ _Float16 Zl[8];           // zero slot for idle lanes

    int wg   = blockIdx.x;
    int orig = (wg & 7) * 320 + (wg >> 3);   // XCD-contiguous remap (bijective)
    int ks    = orig & 1;
    int qg    = (orig >> 1) & 3;
    int bhblk = orig >> 3;
    int blk = bhblk % 20;
    int h   = (bhblk / 20) % 8;
    int b   = bhblk / 160;
    int tid  = threadIdx.x;
    int lane = tid & 63;
    int wv   = tid >> 6;     // 0..3

    const _Float16* base = qkv + (size_t)(b * 96 + h * 12) * HW;
    const _Float16* kb = base + 4 * HW;
    const _Float16* vb = base + 8 * HW;

    const _Float16 h0 = (_Float16)0.f;
    if (tid < 2) *(half4*)&Zl[tid * 4] = half4{ h0, h0, h0, h0 };

    // stage this half's K (key-major) and V^T (+ones row) into LDS
    for (int jj = tid; jj < KEYS2; jj += 256) {
        int j = ks * KEYS2 + jj;
        int yy = j / 40, wc = j - yy * 40;
        int wpos = blk * 24 + wc - 8;
        _Float16 k0 = h0, k1 = h0, k2 = h0, k3 = h0;
        _Float16 v0 = h0, v1 = h0, v2 = h0, v3 = h0;
        if ((unsigned)wpos < 480u) {
            int o = yy * 480 + wpos;
            k0 = kb[o]; k1 = kb[o + HW]; k2 = kb[o + 2 * HW]; k3 = kb[o + 3 * HW];
            v0 = vb[o]; v1 = vb[o + HW]; v2 = vb[o + 2 * HW]; v3 = vb[o + 3 * HW];
        }
        *(half4*)&Kl[jj * 4] = half4{ k0, k1, k2, k3 };
        Vl[jj]           = v0;
        Vl[VS2 + jj]     = v1;
        Vl[2 * VS2 + jj] = v2;
        Vl[3 * VS2 + jj] = v3;
        Vl[4 * VS2 + jj] = (_Float16)1.0f;
    }

    // Q B-frags: lane<16 holds query (tile_base+lane)'s 4 dims (pre-scaled)
    const float QS = 0.5f * 1.44269504f;   // dh^-0.5 * log2(e)
    half4 qf[3];
#pragma unroll
    for (int t = 0; t < 3; ++t) {
        half4 qq = { h0, h0, h0, h0 };
        if (lane < 16) {
            int q = qg * 192 + (wv * 3 + t) * 16 + lane;
            int y = q / 24, qc = q - y * 24;
            int o = y * 480 + blk * 24 + qc;
            qq[0] = (_Float16)((float)base[o] * QS);
            qq[1] = (_Float16)((float)base[o + HW] * QS);
            qq[2] = (_Float16)((float)base[o + 2 * HW] * QS);
            qq[3] = (_Float16)((float)base[o + 3 * HW] * QS);
        }
        qf[t] = qq;
    }

    __syncthreads();

    const floatx4 fz = { 0.f, 0.f, 0.f, 0.f };
    floatx4 acc[3];
#pragma unroll
    for (int t = 0; t < 3; ++t) acc[t] = fz;

    int n = lane & 15;          // A-row (key) for ka; out-dim col for epilogue
    int g = lane >> 4;

    // stride-0 zero-slot pointers for idle lanes (no per-iter cndmask)
    const _Float16* kap = (lane < 16) ? &Kl[n * 4] : Zl;
    int kstep = (lane < 16) ? 64 : 0;              // 16 keys * 4 halves
    const _Float16* vap = (n <= 4) ? &Vl[n * VS2 + g * 4] : Zl;
    int vstep = (n <= 4) ? 16 : 0;                 // 16 halves

    for (int kt = 0; kt < KEYS2 / 16; ++kt) {
        half4 ka = *(const half4*)kap; kap += kstep;
        half4 vv = *(const half4*)vap; vap += vstep;
#pragma unroll
        for (int t = 0; t < 3; ++t) {
            floatx4 s = __builtin_amdgcn_mfma_f32_16x16x16f16(ka, qf[t], fz, 0, 0, 0);
            auto lo = __builtin_amdgcn_cvt_pkrtz(__builtin_amdgcn_exp2f(s[0]),
                                                 __builtin_amdgcn_exp2f(s[1]));
            auto hi = __builtin_amdgcn_cvt_pkrtz(__builtin_amdgcn_exp2f(s[2]),
                                                 __builtin_amdgcn_exp2f(s[3]));
            half4 pa = { (_Float16)lo[0], (_Float16)lo[1],
                         (_Float16)hi[0], (_Float16)hi[1] };
            acc[t] = __builtin_amdgcn_mfma_f32_16x16x16f16(pa, vv, acc[t], 0, 0, 0);
        }
    }

    // write partials: lane holds O'[q=(wv*3+t)*16+g*4+r][n]; n==4 is denom
    float* p = part + ((size_t)(bhblk * 4 + qg) * 2 + ks) * 960;
#pragma unroll
    for (int t = 0; t < 3; ++t) {
#pragma unroll
        for (int r = 0; r < 4; ++r) {
            if (n < 5) {
                int qloc = (wv * 3 + t) * 16 + g * 4 + r;
                p[n * 192 + qloc] = acc[t][r];
            }
        }
    }
}

// ---------------------------------------------------------------------------
// Attention pass 2: combine the 2 key-half partials, normalize, write att f16.
// 960 WGs x 256 = one thread per (bhblk, q).
// ---------------------------------------------------------------------------
__global__ __launch_bounds__(256) void attn_combine(
    const float* __restrict__ part, _Float16* __restrict__ att)
{
    int qglob = blockIdx.x * 256 + threadIdx.x;   // < 320*768
    int bhblk = qglob / 768;
    int q     = qglob - bhblk * 768;
    int qg    = q / 192;
    int qi    = q - qg * 192;
    int blk = bhblk % 20;
    int h   = (bhblk / 20) % 8;
    int b   = bhblk / 160;

    const float* p0 = part + ((size_t)(bhblk * 4 + qg) * 2) * 960;
    const float* p1 = p0 + 960;

    float a0 = p0[qi]           + p1[qi];
    float a1 = p0[192 + qi]     + p1[192 + qi];
    float a2 = p0[2 * 192 + qi] + p1[2 * 192 + qi];
    float a3 = p0[3 * 192 + qi] + p1[3 * 192 + qi];
    float l  = p0[4 * 192 + qi] + p1[4 * 192 + qi];
    float inv = 1.f / l;

    int y = q / 24, qc = q - y * 24;
    _Float16* o = att + ((size_t)(b * 32 + h * 4) * 32 + y) * 480 + blk * 24 + qc;
    o[0]      = (_Float16)(a0 * inv);
    o[HW]     = (_Float16)(a1 * inv);
    o[2 * HW] = (_Float16)(a2 * inv);
    o[3 * HW] = (_Float16)(a3 * inv);
}

extern "C" void kernel_launch(void* const* d_in, const int* in_sizes, int n_in,
                              void* d_out, int out_size, void* d_ws, size_t ws_size,
                              hipStream_t stream) {
    const float* x     = (const float*)d_in[0];
    const float* qkv_w = (const float*)d_in[1];
    const float* qkv_b = (const float*)d_in[2];
    const float* out_w = (const float*)d_in[3];
    float* out = (float*)d_out;

    float* wt1 = (float*)d_ws;                          // 27,648 f32
    float* wt2 = wt1 + 32 * 9 * 96;                     // 9,216 f32
    _Float16* qkv16 = (_Float16*)(wt2 + 32 * 9 * 32);   // 2*96*HW halves (5.9 MB)
    _Float16* att16 = qkv16 + (size_t)2 * 96 * HW;      // 2*32*HW halves (1.9 MB)
    float* part = (float*)(att16 + (size_t)2 * 32 * HW); // 1280*2*960 f32 (9.8 MB)

    // fused weight repack
    repack_both<<<(96 * 288 + 32 * 288 + 255) / 256, 256, 0, stream>>>(
        qkv_w, wt1, out_w, wt2);

    // conv1: x (fp32) -> qkv16 (f16); 2 pixels x 16 co per thread
    conv3x3_w2<16, float, _Float16>
        <<<dim3(30, 2 * 6), 256, 0, stream>>>(x, wt1, qkv_b, qkv16, 96);

    // attention pass 1 (KSPLIT=2, XCD-swizzled): qkv16 -> part
    attn_part<<<2560, 256, 0, stream>>>(qkv16, part);

    // attention pass 2: part -> att16
    attn_combine<<<960, 256, 0, stream>>>(part, att16);

    // conv2: att16 (f16) -> out (fp32); 2 pixels x 8 co per thread
    conv3x3_w2<8, _Float16, float>
        <<<dim3(30, 2 * 4), 256, 0, stream>>>(att16, wt2, nullptr, out, 32);
}

// Round 16
// 106.536 us; speedup vs baseline: 1.4464x; 1.4464x over previous
//
#include <hip/hip_runtime.h>
#include <hip/hip_bf16.h>

// x: (2,32,32,480) fp32; qkv_w: (96,32,3,3); qkv_b: (96,); out_w: (32,32,3,3)
// D_MODEL=32, N_HEADS=8, dh=4, QUERY_SHAPE=24, MEM_FLANGE=8
// H=32, W=480, nb=20, wlen=40; per (b,h,blk): 768 queries x 1280 keys.

#define HW 15360      // 32*480, one channel plane
#define VSTRIDE 1300  // halves; 650 dwords = 10 mod 32 -> max 2-way bank alias

typedef _Float16 half4 __attribute__((ext_vector_type(4)));
typedef float floatx4 __attribute__((ext_vector_type(4)));

// ---------------------------------------------------------------------------
// Repack BOTH weight tensors [Cout][32][3][3] -> [32*9][Cout] in one launch.
// ---------------------------------------------------------------------------
__global__ __launch_bounds__(256) void repack_both(
    const float* __restrict__ w1, float* __restrict__ wt1,
    const float* __restrict__ w2, float* __restrict__ wt2) {
    int i = blockIdx.x * 256 + threadIdx.x;
    if (i < 96 * 288) {
        int co = i / 288, r = i - co * 288;
        wt1[r * 96 + co] = w1[i];
    } else if (i < 96 * 288 + 32 * 288) {
        int i2 = i - 96 * 288;
        int co = i2 / 288, r = i2 - co * 288;
        wt2[r * 32 + co] = w2[i2];
    }
}

// ---------------------------------------------------------------------------
// 3x3 conv, pad 1, NCHW, Cin=32. Each thread: 1 pixel x CO_TILE out-channels.
// Small CO_TILE => many WGs => occupancy/latency hiding (conv is L1-latency
// bound, round-14 lesson: fewer threads with more work/thread regressed).
// ---------------------------------------------------------------------------
template<int CO_TILE, typename TIN, typename TOUT>
__global__ __launch_bounds__(256) void conv3x3_tiled(
    const TIN* __restrict__ in, const float* __restrict__ wt,
    const float* __restrict__ bias, TOUT* __restrict__ out, int Cout)
{
    int nct = Cout / CO_TILE;
    int bc  = blockIdx.y;
    int ct  = bc % nct;
    int b   = bc / nct;
    int co0 = ct * CO_TILE;
    int pix = blockIdx.x * 256 + threadIdx.x;   // < 15360
    int y   = pix / 480;
    int w   = pix - y * 480;

    const TIN* ibase = in + (size_t)b * 32 * HW + y * 480 + w;

    bool ym = y > 0, yp = y < 31, wm = w > 0, wp = w < 479;
    int   off[9];
    float msk[9];
    {
        const bool c[9] = { ym && wm, ym, ym && wp,
                            wm,       true, wp,
                            yp && wm, yp, yp && wp };
        const int  o[9] = { -481, -480, -479, -1, 0, 1, 479, 480, 481 };
#pragma unroll
        for (int k = 0; k < 9; ++k) {
            off[k] = c[k] ? o[k] : 0;
            msk[k] = c[k] ? 1.f : 0.f;
        }
    }

    float acc[CO_TILE];
#pragma unroll
    for (int i = 0; i < CO_TILE; ++i) acc[i] = bias ? bias[co0 + i] : 0.f;

    for (int ci = 0; ci < 32; ++ci) {
        const TIN* ip = ibase + ci * HW;
        float v[9];
#pragma unroll
        for (int k = 0; k < 9; ++k) v[k] = (float)ip[off[k]] * msk[k];

        const float* wrow = wt + ci * 9 * Cout + co0;
#pragma unroll
        for (int k = 0; k < 9; ++k) {
            float xv = v[k];
            const float4* w4p = (const float4*)(wrow + k * Cout);
#pragma unroll
            for (int c = 0; c < CO_TILE / 4; ++c) {
                float4 ww = w4p[c];
                acc[c * 4 + 0] += xv * ww.x;
                acc[c * 4 + 1] += xv * ww.y;
                acc[c * 4 + 2] += xv * ww.z;
                acc[c * 4 + 3] += xv * ww.w;
            }
        }
    }

    size_t obase = (size_t)(b * Cout + co0) * HW + pix;
#pragma unroll
    for (int i = 0; i < CO_TILE; ++i) out[obase + (size_t)i * HW] = (TOUT)acc[i];
}

// ---------------------------------------------------------------------------
// MFMA flash attention (round-13 known-good, 52.7 us).
// Grid: 1280 WGs = (b,h,blk) x 4 query-groups, XCD-swizzled so the 4 groups
// sharing one K/V window land on one XCD's L2. 256 threads (4 waves), each
// wave 3 q-tiles of 16 queries. S' = K·Q^T via mfma_16x16x16_f16 (swapped
// operands: C-frag of S' == A-frag of P), exp2 in-register, P·[V|1|0] second
// MFMA; ones-row of V^T yields the softmax denominator free. Idle fragment
// lanes read a zeroed LDS slot with stride 0.
// ---------------------------------------------------------------------------
__global__ __launch_bounds__(256) void attn_mfma(
    const _Float16* __restrict__ qkv, _Float16* __restrict__ att)
{
    __shared__ _Float16 Kl[1280 * 4];      // [j][d] key-major, 8B/key
    __shared__ _Float16 Vl[5 * VSTRIDE];   // [n][j] transposed; row 4 = ones
    __shared__ _Float16 Zl[8];             // zero slot for idle lanes

    int wg    = blockIdx.x;
    int orig  = (wg & 7) * 160 + (wg >> 3);   // XCD-contiguous remap (bijective)
    int qg    = orig & 3;
    int bhblk = orig >> 2;
    int blk = bhblk % 20;
    int h   = (bhblk / 20) % 8;
    int b   = bhblk / 160;
    int tid  = threadIdx.x;
    int lane = tid & 63;
    int wv   = tid >> 6;     // 0..3

    const _Float16* base = qkv + (size_t)(b * 96 + h * 12) * HW;
    const _Float16* kb = base + 4 * HW;
    const _Float16* vb = base + 8 * HW;

    const _Float16 h0 = (_Float16)0.f;
    if (tid < 2) *(half4*)&Zl[tid * 4] = half4{ h0, h0, h0, h0 };

    // stage K (key-major) and V^T (+ones row) into LDS
    for (int j = tid; j < 1280; j += 256) {
        int yy = j / 40, wc = j - yy * 40;
        int wpos = blk * 24 + wc - 8;
        _Float16 k0 = h0, k1 = h0, k2 = h0, k3 = h0;
        _Float16 v0 = h0, v1 = h0, v2 = h0, v3 = h0;
        if ((unsigned)wpos < 480u) {
            int o = yy * 480 + wpos;
            k0 = kb[o]; k1 = kb[o + HW]; k2 = kb[o + 2 * HW]; k3 = kb[o + 3 * HW];
            v0 = vb[o]; v1 = vb[o + HW]; v2 = vb[o + 2 * HW]; v3 = vb[o + 3 * HW];
        }
        *(half4*)&Kl[j * 4] = half4{ k0, k1, k2, k3 };
        Vl[j]               = v0;
        Vl[VSTRIDE + j]     = v1;
        Vl[2 * VSTRIDE + j] = v2;
        Vl[3 * VSTRIDE + j] = v3;
        Vl[4 * VSTRIDE + j] = (_Float16)1.0f;
    }

    // Q B-frags: lane<16 holds query (tile_base+lane)'s 4 dims (pre-scaled)
    const float QS = 0.5f * 1.44269504f;   // dh^-0.5 * log2(e)
    half4 qf[3];
#pragma unroll
    for (int t = 0; t < 3; ++t) {
        half4 qq = { h0, h0, h0, h0 };
        if (lane < 16) {
            int q = qg * 192 + (wv * 3 + t) * 16 + lane;
            int y = q / 24, qc = q - y * 24;
            int o = y * 480 + blk * 24 + qc;
            qq[0] = (_Float16)((float)base[o] * QS);
            qq[1] = (_Float16)((float)base[o + HW] * QS);
            qq[2] = (_Float16)((float)base[o + 2 * HW] * QS);
            qq[3] = (_Float16)((float)base[o + 3 * HW] * QS);
        }
        qf[t] = qq;
    }

    __syncthreads();

    const floatx4 fz = { 0.f, 0.f, 0.f, 0.f };
    floatx4 acc[3];
#pragma unroll
    for (int t = 0; t < 3; ++t) acc[t] = fz;

    int n = lane & 15;          // A-row (key) for ka; B-col (out dim) for vv
    int g = lane >> 4;

    // stride-0 zero-slot pointers for idle lanes (replaces per-iter cndmask)
    const _Float16* kap = (lane < 16) ? &Kl[n * 4] : Zl;
    int kstep = (lane < 16) ? 64 : 0;              // 16 keys * 4 halves
    const _Float16* vap = (n <= 4) ? &Vl[n * VSTRIDE + g * 4] : Zl;
    int vstep = (n <= 4) ? 16 : 0;                 // 16 halves

    for (int kt = 0; kt < 80; ++kt) {
        half4 ka = *(const half4*)kap; kap += kstep;
        half4 vv = *(const half4*)vap; vap += vstep;
#pragma unroll
        for (int t = 0; t < 3; ++t) {
            floatx4 s = __builtin_amdgcn_mfma_f32_16x16x16f16(ka, qf[t], fz, 0, 0, 0);
            auto lo = __builtin_amdgcn_cvt_pkrtz(__builtin_amdgcn_exp2f(s[0]),
                                                 __builtin_amdgcn_exp2f(s[1]));
            auto hi = __builtin_amdgcn_cvt_pkrtz(__builtin_amdgcn_exp2f(s[2]),
                                                 __builtin_amdgcn_exp2f(s[3]));
            half4 pa = { (_Float16)lo[0], (_Float16)lo[1],
                         (_Float16)hi[0], (_Float16)hi[1] };
            acc[t] = __builtin_amdgcn_mfma_f32_16x16x16f16(pa, vv, acc[t], 0, 0, 0);
        }
    }

    // epilogue: lane holds O[q = tile+g*4+r][n]; col 4 = softmax denominator
#pragma unroll
    for (int t = 0; t < 3; ++t) {
#pragma unroll
        for (int r = 0; r < 4; ++r) {
            float ls = __shfl(acc[t][r], (lane & 48) + 4);
            if (n < 4) {
                float val = acc[t][r] * __builtin_amdgcn_rcpf(ls);
                int q = qg * 192 + (wv * 3 + t) * 16 + g * 4 + r;
                int y = q / 24, qc = q - y * 24;
                att[((size_t)(b * 32 + h * 4 + n) * 32 + y) * 480 + blk * 24 + qc] =
                    (_Float16)val;
            }
        }
    }
}

extern "C" void kernel_launch(void* const* d_in, const int* in_sizes, int n_in,
                              void* d_out, int out_size, void* d_ws, size_t ws_size,
                              hipStream_t stream) {
    const float* x     = (const float*)d_in[0];
    const float* qkv_w = (const float*)d_in[1];
    const float* qkv_b = (const float*)d_in[2];
    const float* out_w = (const float*)d_in[3];
    float* out = (float*)d_out;

    float* wt1 = (float*)d_ws;                          // 27,648 f32
    float* wt2 = wt1 + 32 * 9 * 96;                     // 9,216 f32
    _Float16* qkv16 = (_Float16*)(wt2 + 32 * 9 * 32);   // 2*96*HW halves (5.9 MB)
    _Float16* att16 = qkv16 + (size_t)2 * 96 * HW;      // 2*32*HW halves (1.9 MB)

    // fused weight repack
    repack_both<<<(96 * 288 + 32 * 288 + 255) / 256, 256, 0, stream>>>(
        qkv_w, wt1, out_w, wt2);

    // conv1: x (fp32) -> qkv16 (f16); 1 pixel x 8 co per thread, 1440 WGs
    conv3x3_tiled<8, float, _Float16>
        <<<dim3(60, 2 * 12), 256, 0, stream>>>(x, wt1, qkv_b, qkv16, 96);

    // attention (MFMA flash, XCD-swizzled): qkv16 -> att16
    attn_mfma<<<1280, 256, 0, stream>>>(qkv16, att16);

    // conv2: att16 (f16) -> out (fp32); 1 pixel x 4 co per thread, 960 WGs
    conv3x3_tiled<4, _Float16, float>
        <<<dim3(60, 2 * 8), 256, 0, stream>>>(att16, wt2, nullptr, out, 32);
}

// Round 17
// 103.498 us; speedup vs baseline: 1.4889x; 1.0294x over previous
//
#include <hip/hip_runtime.h>
#include <hip/hip_bf16.h>

// x: (2,32,32,480) fp32; qkv_w: (96,32,3,3); qkv_b: (96,); out_w: (32,32,3,3)
// D_MODEL=32, N_HEADS=8, dh=4, QUERY_SHAPE=24, MEM_FLANGE=8
// H=32, W=480, nb=20, wlen=40; per (b,h,blk): 768 queries x 1280 keys.

#define HW 15360      // 32*480, one channel plane
#define VSTRIDE 1300  // halves; 650 dwords = 10 mod 32 -> max 2-way bank alias

typedef _Float16 half4 __attribute__((ext_vector_type(4)));
typedef float floatx4 __attribute__((ext_vector_type(4)));
// exact half2 flavor the amdgcn builtins use (round-11 lesson: don't guess)
using fh2 = decltype(__builtin_amdgcn_cvt_pkrtz(0.f, 0.f));

// ---------------------------------------------------------------------------
// Repack BOTH weight tensors [Cout][32][3][3] -> packed-f16 pairs over ci:
// wtu[(ci2*9 + tap)*Cout + co] = pack_f16(w[co][2ci2][tap], w[co][2ci2+1][tap])
// ---------------------------------------------------------------------------
__global__ __launch_bounds__(256) void repack_both(
    const float* __restrict__ w1, unsigned* __restrict__ wt1,
    const float* __restrict__ w2, unsigned* __restrict__ wt2) {
    int i = blockIdx.x * 256 + threadIdx.x;
    if (i < 96 * 144) {
        int co = i / 144, r = i - co * 144;
        int ci2 = r / 9, tap = r - ci2 * 9;
        float a = w1[co * 288 + (2 * ci2) * 9 + tap];
        float b = w1[co * 288 + (2 * ci2) * 9 + 9 + tap];
        fh2 p = __builtin_amdgcn_cvt_pkrtz(a, b);
        wt1[(ci2 * 9 + tap) * 96 + co] = __builtin_bit_cast(unsigned, p);
    } else if (i < 96 * 144 + 32 * 144) {
        int i2 = i - 96 * 144;
        int co = i2 / 144, r = i2 - co * 144;
        int ci2 = r / 9, tap = r - ci2 * 9;
        float a = w2[co * 288 + (2 * ci2) * 9 + tap];
        float b = w2[co * 288 + (2 * ci2) * 9 + 9 + tap];
        fh2 p = __builtin_amdgcn_cvt_pkrtz(a, b);
        wt2[(ci2 * 9 + tap) * 32 + co] = __builtin_bit_cast(unsigned, p);
    }
}

// ---------------------------------------------------------------------------
// 3x3 conv, pad 1, NCHW, Cin=32, fp32 input. Each thread: 1 pixel x CO_TILE
// out-channels. Inner math: v_dot2_f32_f16 (2 f16 MACs, fp32 accumulate) over
// ci-pairs — halves VALU issue vs fp32 FMA. Weights pre-packed by repack_both.
// ---------------------------------------------------------------------------
template<int CO_TILE, typename TOUT>
__global__ __launch_bounds__(256) void conv3x3_dot2(
    const float* __restrict__ in, const unsigned* __restrict__ wt,
    const float* __restrict__ bias, TOUT* __restrict__ out, int Cout)
{
    int nct = Cout / CO_TILE;
    int bc  = blockIdx.y;
    int ct  = bc % nct;
    int b   = bc / nct;
    int co0 = ct * CO_TILE;
    int pix = blockIdx.x * 256 + threadIdx.x;   // < 15360
    int y   = pix / 480;
    int w   = pix - y * 480;

    const float* ibase = in + (size_t)b * 32 * HW + y * 480 + w;

    bool ym = y > 0, yp = y < 31, wm = w > 0, wp = w < 479;
    int   off[9];
    float msk[9];
    {
        const bool c[9] = { ym && wm, ym, ym && wp,
                            wm,       true, wp,
                            yp && wm, yp, yp && wp };
        const int  o[9] = { -481, -480, -479, -1, 0, 1, 479, 480, 481 };
#pragma unroll
        for (int k = 0; k < 9; ++k) {
            off[k] = c[k] ? o[k] : 0;
            msk[k] = c[k] ? 1.f : 0.f;
        }
    }

    float acc[CO_TILE];
#pragma unroll
    for (int i = 0; i < CO_TILE; ++i) acc[i] = bias ? bias[co0 + i] : 0.f;

    for (int ci2 = 0; ci2 < 16; ++ci2) {
        const float* ipA = ibase + (2 * ci2) * HW;
        const float* ipB = ipA + HW;
        fh2 v2[9];
#pragma unroll
        for (int k = 0; k < 9; ++k)
            v2[k] = __builtin_amdgcn_cvt_pkrtz(ipA[off[k]] * msk[k],
                                               ipB[off[k]] * msk[k]);

        const unsigned* wrow = wt + (ci2 * 9) * Cout + co0;
#pragma unroll
        for (int k = 0; k < 9; ++k) {
            const uint4* w4p = (const uint4*)(wrow + k * Cout);
#pragma unroll
            for (int c = 0; c < CO_TILE / 4; ++c) {
                uint4 ww = w4p[c];
                acc[c * 4 + 0] = __builtin_amdgcn_fdot2(
                    v2[k], __builtin_bit_cast(fh2, ww.x), acc[c * 4 + 0], false);
                acc[c * 4 + 1] = __builtin_amdgcn_fdot2(
                    v2[k], __builtin_bit_cast(fh2, ww.y), acc[c * 4 + 1], false);
                acc[c * 4 + 2] = __builtin_amdgcn_fdot2(
                    v2[k], __builtin_bit_cast(fh2, ww.z), acc[c * 4 + 2], false);
                acc[c * 4 + 3] = __builtin_amdgcn_fdot2(
                    v2[k], __builtin_bit_cast(fh2, ww.w), acc[c * 4 + 3], false);
            }
        }
    }

    size_t obase = (size_t)(b * Cout + co0) * HW + pix;
#pragma unroll
    for (int i = 0; i < CO_TILE; ++i) out[obase + (size_t)i * HW] = (TOUT)acc[i];
}

// ---------------------------------------------------------------------------
// MFMA flash attention (round-13/16 known-good, 52.7 us; output now f32).
// Grid: 1280 WGs = (b,h,blk) x 4 query-groups, XCD-swizzled. 256 threads
// (4 waves), each wave 3 q-tiles of 16 queries. S' = K·Q^T via
// mfma_16x16x16_f16 (swapped operands: C-frag of S' == A-frag of P), exp2
// in-register, P·[V|1|0] second MFMA; ones-row of V^T gives the denominator.
// Idle fragment lanes read a zeroed LDS slot with stride 0.
// ---------------------------------------------------------------------------
__global__ __launch_bounds__(256) void attn_mfma(
    const _Float16* __restrict__ qkv, float* __restrict__ att)
{
    __shared__ _Float16 Kl[1280 * 4];      // [j][d] key-major, 8B/key
    __shared__ _Float16 Vl[5 * VSTRIDE];   // [n][j] transposed; row 4 = ones
    __shared__ _Float16 Zl[8];             // zero slot for idle lanes

    int wg    = blockIdx.x;
    int orig  = (wg & 7) * 160 + (wg >> 3);   // XCD-contiguous remap (bijective)
    int qg    = orig & 3;
    int bhblk = orig >> 2;
    int blk = bhblk % 20;
    int h   = (bhblk / 20) % 8;
    int b   = bhblk / 160;
    int tid  = threadIdx.x;
    int lane = tid & 63;
    int wv   = tid >> 6;     // 0..3

    const _Float16* base = qkv + (size_t)(b * 96 + h * 12) * HW;
    const _Float16* kb = base + 4 * HW;
    const _Float16* vb = base + 8 * HW;

    const _Float16 h0 = (_Float16)0.f;
    if (tid < 2) *(half4*)&Zl[tid * 4] = half4{ h0, h0, h0, h0 };

    // stage K (key-major) and V^T (+ones row) into LDS
    for (int j = tid; j < 1280; j += 256) {
        int yy = j / 40, wc = j - yy * 40;
        int wpos = blk * 24 + wc - 8;
        _Float16 k0 = h0, k1 = h0, k2 = h0, k3 = h0;
        _Float16 v0 = h0, v1 = h0, v2 = h0, v3 = h0;
        if ((unsigned)wpos < 480u) {
            int o = yy * 480 + wpos;
            k0 = kb[o]; k1 = kb[o + HW]; k2 = kb[o + 2 * HW]; k3 = kb[o + 3 * HW];
            v0 = vb[o]; v1 = vb[o + HW]; v2 = vb[o + 2 * HW]; v3 = vb[o + 3 * HW];
        }
        *(half4*)&Kl[j * 4] = half4{ k0, k1, k2, k3 };
        Vl[j]               = v0;
        Vl[VSTRIDE + j]     = v1;
        Vl[2 * VSTRIDE + j] = v2;
        Vl[3 * VSTRIDE + j] = v3;
        Vl[4 * VSTRIDE + j] = (_Float16)1.0f;
    }

    // Q B-frags: lane<16 holds query (tile_base+lane)'s 4 dims (pre-scaled)
    const float QS = 0.5f * 1.44269504f;   // dh^-0.5 * log2(e)
    half4 qf[3];
#pragma unroll
    for (int t = 0; t < 3; ++t) {
        half4 qq = { h0, h0, h0, h0 };
        if (lane < 16) {
            int q = qg * 192 + (wv * 3 + t) * 16 + lane;
            int y = q / 24, qc = q - y * 24;
            int o = y * 480 + blk * 24 + qc;
            qq[0] = (_Float16)((float)base[o] * QS);
            qq[1] = (_Float16)((float)base[o + HW] * QS);
            qq[2] = (_Float16)((float)base[o + 2 * HW] * QS);
            qq[3] = (_Float16)((float)base[o + 3 * HW] * QS);
        }
        qf[t] = qq;
    }

    __syncthreads();

    const floatx4 fz = { 0.f, 0.f, 0.f, 0.f };
    floatx4 acc[3];
#pragma unroll
    for (int t = 0; t < 3; ++t) acc[t] = fz;

    int n = lane & 15;          // A-row (key) for ka; B-col (out dim) for vv
    int g = lane >> 4;

    // stride-0 zero-slot pointers for idle lanes (replaces per-iter cndmask)
    const _Float16* kap = (lane < 16) ? &Kl[n * 4] : Zl;
    int kstep = (lane < 16) ? 64 : 0;              // 16 keys * 4 halves
    const _Float16* vap = (n <= 4) ? &Vl[n * VSTRIDE + g * 4] : Zl;
    int vstep = (n <= 4) ? 16 : 0;                 // 16 halves

    for (int kt = 0; kt < 80; ++kt) {
        half4 ka = *(const half4*)kap; kap += kstep;
        half4 vv = *(const half4*)vap; vap += vstep;
#pragma unroll
        for (int t = 0; t < 3; ++t) {
            floatx4 s = __builtin_amdgcn_mfma_f32_16x16x16f16(ka, qf[t], fz, 0, 0, 0);
            auto lo = __builtin_amdgcn_cvt_pkrtz(__builtin_amdgcn_exp2f(s[0]),
                                                 __builtin_amdgcn_exp2f(s[1]));
            auto hi = __builtin_amdgcn_cvt_pkrtz(__builtin_amdgcn_exp2f(s[2]),
                                                 __builtin_amdgcn_exp2f(s[3]));
            half4 pa = { (_Float16)lo[0], (_Float16)lo[1],
                         (_Float16)hi[0], (_Float16)hi[1] };
            acc[t] = __builtin_amdgcn_mfma_f32_16x16x16f16(pa, vv, acc[t], 0, 0, 0);
        }
    }

    // epilogue: lane holds O[q = tile+g*4+r][n]; col 4 = softmax denominator
#pragma unroll
    for (int t = 0; t < 3; ++t) {
#pragma unroll
        for (int r = 0; r < 4; ++r) {
            float ls = __shfl(acc[t][r], (lane & 48) + 4);
            if (n < 4) {
                float val = acc[t][r] * __builtin_amdgcn_rcpf(ls);
                int q = qg * 192 + (wv * 3 + t) * 16 + g * 4 + r;
                int y = q / 24, qc = q - y * 24;
                att[((size_t)(b * 32 + h * 4 + n) * 32 + y) * 480 + blk * 24 + qc] = val;
            }
        }
    }
}

extern "C" void kernel_launch(void* const* d_in, const int* in_sizes, int n_in,
                              void* d_out, int out_size, void* d_ws, size_t ws_size,
                              hipStream_t stream) {
    const float* x     = (const float*)d_in[0];
    const float* qkv_w = (const float*)d_in[1];
    const float* qkv_b = (const float*)d_in[2];
    const float* out_w = (const float*)d_in[3];
    float* out = (float*)d_out;

    unsigned* wt1 = (unsigned*)d_ws;                    // 96*144 = 13,824 u32
    unsigned* wt2 = wt1 + 96 * 144;                     // 32*144 = 4,608 u32
    _Float16* qkv16 = (_Float16*)(wt2 + 32 * 144);      // 2*96*HW halves (5.9 MB)
    float* attf = (float*)(qkv16 + (size_t)2 * 96 * HW); // 2*32*HW f32 (3.9 MB)

    // fused weight repack (packed-f16 ci-pairs)
    repack_both<<<(96 * 144 + 32 * 144 + 255) / 256, 256, 0, stream>>>(
        qkv_w, wt1, out_w, wt2);

    // conv1: x (fp32) -> qkv16 (f16); dot2 math; 1 pixel x 8 co, 1440 WGs
    conv3x3_dot2<8, _Float16>
        <<<dim3(60, 2 * 12), 256, 0, stream>>>(x, wt1, qkv_b, qkv16, 96);

    // attention (MFMA flash, XCD-swizzled): qkv16 -> attf (f32)
    attn_mfma<<<1280, 256, 0, stream>>>(qkv16, attf);

    // conv2: attf (f32) -> out (fp32); dot2 math; 1 pixel x 4 co, 960 WGs
    conv3x3_dot2<4, float>
        <<<dim3(60, 2 * 8), 256, 0, stream>>>(attf, wt2, nullptr, out, 32);
}